// Round 6
// baseline (241.721 us; speedup 1.0000x reference)
//
#include <hip/hip_runtime.h>
#include <hip/hip_bf16.h>

#define L_ 2048
#define D_ 192
#define HK_ 48
#define EPS_ 1e-3f
#define SCALE_ 0.28867513459481287f  // 1/sqrt(12)
#define LOG2E_ 1.4426950408889634f

typedef __hip_bfloat16 bf16;
typedef _Float16 f16;
typedef __fp16 hf16x2 __attribute__((ext_vector_type(2)));   // builtin return type
typedef _Float16 f16x4 __attribute__((ext_vector_type(4)));
typedef __bf16 bf16x4 __attribute__((ext_vector_type(4)));
typedef __bf16 bf16x8 __attribute__((ext_vector_type(8)));
typedef float  f32x4  __attribute__((ext_vector_type(4)));

__device__ __forceinline__ float b2f(bf16 x) { return __bfloat162float(x); }
__device__ __forceinline__ bf16 f2b(float x) { return __float2bfloat16(x); }

// ---------------------------------------------------------------------------
// K0: single prep kernel — all weight repacks in one launch (unchanged).
// ---------------------------------------------------------------------------
__global__ __launch_bounds__(256) void k_prep_all(
    const float* __restrict__ c1w, const float* __restrict__ c2w,
    const float* __restrict__ wq, const float* __restrict__ wk, const float* __restrict__ wv,
    const float* __restrict__ bq, const float* __restrict__ bk, const float* __restrict__ bv,
    const float* __restrict__ wo,
    bf16* __restrict__ wrep1, bf16* __restrict__ wrep2,
    bf16* __restrict__ wrepq, float* __restrict__ bias144, bf16* __restrict__ wrepo)
{
    const int i = blockIdx.x * 256 + threadIdx.x;
    if (i < 110592) {
        const int k = i / 192, n = i - k * 192;
        wrep1[((size_t)(k >> 5) * 192 + n) * 32 + (k & 31)] = f2b(c1w[i]);
    } else if (i < 221184) {
        const int j = i - 110592;
        const int k = j / 192, n = j - k * 192;
        wrep2[((size_t)(k >> 5) * 192 + n) * 32 + (k & 31)] = f2b(c2w[j]);
    } else if (i < 248832) {
        const int j = i - 221184;
        const int kb = j / 4608, rem = j % 4608;
        const int n = rem / 32, kk = rem % 32;
        const int k = kb * 32 + kk;
        float v;
        if (n < 48)       v = wq[k * HK_ + n] * (SCALE_ * LOG2E_);
        else if (n < 96)  v = wk[k * HK_ + (n - 48)];
        else              v = wv[k * HK_ + (n - 96)];
        wrepq[j] = f2b(v);
    } else if (i < 248976) {
        const int j = i - 248832;
        bias144[j] = (j < 48) ? bq[j] * (SCALE_ * LOG2E_)
                   : (j < 96) ? bk[j - 48] : bv[j - 96];
    } else if (i < 261264) {
        const int j = i - 248976;
        const int kb = j / 6144, rem = j % 6144;
        const int n = rem / 32, kk = rem % 32;
        const int k = kb * 32 + kk;
        wrepo[j] = f2b(k < 48 ? wo[k * D_ + n] : 0.f);
    }
}

// ---------------------------------------------------------------------------
// K1: fused LN1 + QKV projection via MFMA (unchanged; q/k head-contiguous
// [b*4+h][2048][12]).
// ---------------------------------------------------------------------------
__global__ __launch_bounds__(256, 4) void k_ln_qkv(
    const float* __restrict__ x, const float* __restrict__ g1, const float* __restrict__ b1,
    const bf16* __restrict__ wrep, const float* __restrict__ bias144,
    f16* __restrict__ qo, f16* __restrict__ ko, f16* __restrict__ vt)
{
    __shared__ bf16 xn[32 * 200];
    const int tid = threadIdx.x;
    const int wave = tid >> 6, lane = tid & 63;
    const int rowbase = blockIdx.x * 32;
    const int b = rowbase >> 11;
    const int lrow0 = rowbase & 2047;

    const float gg0 = g1[lane], gg1 = g1[lane + 64], gg2 = g1[lane + 128];
    const float bb0 = b1[lane], bb1 = b1[lane + 64], bb2 = b1[lane + 128];
    for (int i = 0; i < 8; ++i) {
        const int r = wave * 8 + i;
        const float* xp = x + (size_t)(rowbase + r) * D_;
        const float x0 = xp[lane];
        const float x1 = xp[lane + 64];
        const float x2 = xp[lane + 128];
        float s = x0 + x1 + x2;
        float q = x0 * x0 + x1 * x1 + x2 * x2;
        #pragma unroll
        for (int m = 1; m < 64; m <<= 1) {
            s += __shfl_xor(s, m, 64);
            q += __shfl_xor(q, m, 64);
        }
        const float mean = s * (1.0f / 192.0f);
        const float var  = q * (1.0f / 192.0f) - mean * mean;
        const float rs   = rsqrtf(var + EPS_);
        xn[r * 200 + lane]       = f2b((x0 - mean) * rs * gg0 + bb0);
        xn[r * 200 + lane + 64]  = f2b((x1 - mean) * rs * gg1 + bb1);
        xn[r * 200 + lane + 128] = f2b((x2 - mean) * rs * gg2 + bb2);
    }

    if (tid < 128) {
        const int h  = tid >> 5;
        const int vc = 12 + ((tid >> 3) & 3);
        const int p0 = lrow0 + (tid & 7) * 4;
        f16x4 vv;
        vv[0] = vv[1] = vv[2] = vv[3] = (vc == 12) ? (f16)1.0f : (f16)0.0f;
        *(f16x4*)(vt + ((size_t)(b * 4 + h) * 16 + vc) * 2048 + p0) = vv;
    }
    __syncthreads();

    const int l15 = lane & 15, q4 = lane >> 4;
    const int rt = wave >> 1, g = wave & 1;
    const int ntlim = 5 - g;                 // g=0: nt 0..4, g=1: nt 0..3 (+5)
    f32x4 acc[5];
    #pragma unroll
    for (int nt = 0; nt < 5; ++nt) acc[nt] = (f32x4){0.f, 0.f, 0.f, 0.f};

    const bf16* xrow = xn + (rt * 16 + l15) * 200 + q4 * 8;
    #pragma unroll
    for (int kb = 0; kb < 6; ++kb) {
        const bf16x8 a = *(const bf16x8*)(xrow + kb * 32);
        const bf16* wp = wrep + ((size_t)kb * 144 + l15) * 32 + q4 * 8
                       + (size_t)(g * 5) * 16 * 32;
        #pragma unroll
        for (int nt = 0; nt < 5; ++nt) {
            if (nt < ntlim) {
                const bf16x8 bfr = *(const bf16x8*)(wp + (size_t)nt * 16 * 32);
                acc[nt] = __builtin_amdgcn_mfma_f32_16x16x32_bf16(a, bfr, acc[nt], 0, 0, 0);
            }
        }
    }

    const int lr0 = lrow0 + rt * 16 + q4 * 4;
    #pragma unroll
    for (int nt = 0; nt < 5; ++nt) {
        if (nt < ntlim) {
            const int ntg = g * 5 + nt;
            const int col = ntg * 16 + l15;
            const float bd = bias144[col];
            if (ntg < 3) {
                const int h2 = col / 12, c12 = col - h2 * 12;
                #pragma unroll
                for (int reg = 0; reg < 4; ++reg)
                    qo[((size_t)(b * 4 + h2) * 2048 + lr0 + reg) * 12 + c12] =
                        (f16)(acc[nt][reg] + bd);
            } else if (ntg < 6) {
                const int ck = col - 48;
                const int h2 = ck / 12, c12 = ck - h2 * 12;
                #pragma unroll
                for (int reg = 0; reg < 4; ++reg)
                    ko[((size_t)(b * 4 + h2) * 2048 + lr0 + reg) * 12 + c12] =
                        (f16)(acc[nt][reg] + bd);
            } else {
                const int vcol = col - 96;
                const int h = vcol / 12, c12 = vcol % 12;
                f16x4 vv;
                #pragma unroll
                for (int reg = 0; reg < 4; ++reg) vv[reg] = (f16)(acc[nt][reg] + bd);
                *(f16x4*)(vt + ((size_t)(b * 4 + h) * 16 + c12) * 2048 +
                          lrow0 + rt * 16 + q4 * 4) = vv;
            }
        }
    }
}

// ---------------------------------------------------------------------------
// K2: flash attention, Round-6 repair. Round-5's 63 µs came from a serial
// 128-tile k-loop with only distance-1 pair prefetch (4 loads in flight vs
// ~600cy L3 latency) at 22.7% occupancy. Fix:
//  - block = (bh, 64-row strip), grid 2048 (8 blocks/CU); wave = 16 q-rows.
//    ngroups = strip+1 is IDENTICAL for all 4 waves (ntot = 4*strip+wv+1,
//    ceil/4 = strip+1) -> no intra-block divergence; overshoot tiles in the
//    last group are killed by the always-on causal select and all reads stay
//    in bounds (64*(strip+1) <= 2048). Strips launch heavy-first.
//  - group-of-4 k-tiles with 2-unrolled double buffer (named KA/KB/VA/VB,
//    compile-time indices): 8 loads in flight under ~350cy of MFMA+exp2.
// ---------------------------------------------------------------------------
__global__ __launch_bounds__(256, 8) void k_attn(
    const f16* __restrict__ qh, const f16* __restrict__ kh, const f16* __restrict__ vt,
    bf16* __restrict__ ctx)
{
    const int tid = threadIdx.x;
    const int wv = tid >> 6, lane = tid & 63;
    const int quad = lane >> 4, l15 = lane & 15;
    const int bh = blockIdx.x & 63;
    const int strip = 31 - (blockIdx.x >> 6);
    const int b = bh >> 2, h = bh & 3;
    const size_t base  = (size_t)bh * 2048 * 12;
    const size_t vbase = ((size_t)bh * 16 + l15) * 2048;
    const int qw = strip * 64 + wv * 16;    // wave's first q row
    const int qg = qw + l15;                // this lane's q row (score col)
    const int ngroups = strip + 1;          // block-uniform

    f16x4 Qf;
    if (quad < 3)
        Qf = *(const f16x4*)(qh + base + (size_t)(qw + l15) * 12 + quad * 4);
    else { Qf[0] = (f16)LOG2E_; Qf[1] = 0; Qf[2] = 0; Qf[3] = 0; }   // hd12 = log2e

    f32x4 O = (f32x4){0.f, 0.f, 0.f, 0.f};

    f16x4 KA[4], VA[4], KB[4], VB[4];

    auto LOADG = [&](f16x4* K, f16x4* V, int g) {
        const int t0 = g * 4;
        #pragma unroll
        for (int u = 0; u < 4; ++u) {
            if (quad < 3)
                K[u] = *(const f16x4*)(kh + base + (size_t)((t0 + u) * 16 + l15) * 12 + quad * 4);
            else { K[u][0] = (f16)-6.0f; K[u][1] = 0; K[u][2] = 0; K[u][3] = 0; } // hd12 = -6
            V[u] = *(const f16x4*)(vt + vbase + (t0 + u) * 16 + quad * 4);
        }
    };
    auto COMPUTE = [&](const f16x4* K, const f16x4* V, int g) {
        const int t0 = g * 4;
        #pragma unroll
        for (int u = 0; u < 4; ++u) {
            f32x4 sc = (f32x4){0.f, 0.f, 0.f, 0.f};
            sc = __builtin_amdgcn_mfma_f32_16x16x16f16(K[u], Qf, sc, 0, 0, 0);
            const int k0 = (t0 + u) * 16 + quad * 4;
            float p0 = __builtin_amdgcn_exp2f(sc[0]);
            float p1 = __builtin_amdgcn_exp2f(sc[1]);
            float p2 = __builtin_amdgcn_exp2f(sc[2]);
            float p3 = __builtin_amdgcn_exp2f(sc[3]);
            p0 = (k0 + 0 <= qg) ? p0 : 0.f;   // always-on causal select:
            p1 = (k0 + 1 <= qg) ? p1 : 0.f;   // true for all fully-unmasked
            p2 = (k0 + 2 <= qg) ? p2 : 0.f;   // tiles, zeroes overshoot tiles
            p3 = (k0 + 3 <= qg) ? p3 : 0.f;
            const hf16x2 lo = __builtin_amdgcn_cvt_pkrtz(p0, p1);
            const hf16x2 hi = __builtin_amdgcn_cvt_pkrtz(p2, p3);
            f16x4 p;
            p[0] = (f16)lo[0]; p[1] = (f16)lo[1];
            p[2] = (f16)hi[0]; p[3] = (f16)hi[1];
            O = __builtin_amdgcn_mfma_f32_16x16x16f16(p, V[u], O, 0, 0, 0);
        }
    };

    LOADG(KA, VA, 0);
    int g = 0;
    while (true) {
        if (g + 1 < ngroups) LOADG(KB, VB, g + 1);
        COMPUTE(KA, VA, g);
        ++g; if (g >= ngroups) break;
        if (g + 1 < ngroups) LOADG(KA, VA, g + 1);
        COMPUTE(KB, VB, g);
        ++g; if (g >= ngroups) break;
    }

    // epilogue: normalize by l (accumulated in col 12 via ones-column of V)
    const int src = (quad << 4) + 12;
    #pragma unroll
    for (int j = 0; j < 4; ++j) {
        const float li  = __shfl(O[j], src, 64);
        const float inv = __builtin_amdgcn_rcpf(li);
        if (l15 < 12)
            ctx[(size_t)(b * 2048 + qw + quad * 4 + j) * 48 + h * 12 + l15]
                = f2b(O[j] * inv);
    }
}

// ---------------------------------------------------------------------------
// K3: out-proj (MFMA) + residual + LN2 (unchanged from round 5).
// ---------------------------------------------------------------------------
__global__ __launch_bounds__(256, 4) void k_proj_ln2(
    const float* __restrict__ x, const bf16* __restrict__ ctx,
    const bf16* __restrict__ wrepo,
    const float* __restrict__ bo, const float* __restrict__ g2,
    const float* __restrict__ lb2, bf16* __restrict__ x2b,
    bf16* __restrict__ xn2b)
{
    __shared__ bf16 ct[32 * 72];
    __shared__ float psum[4][4][4][2];   // [wave][q4][reg][{sum,ssum}]
    const int tid = threadIdx.x;
    const int wave = tid >> 6, lane = tid & 63;
    const int rowbase = blockIdx.x * 32;

    {
        const int row6 = tid / 6, c6 = tid - row6 * 6;
        if (tid < 192) {
            const bf16x8 v = *(const bf16x8*)(ctx + (size_t)(rowbase + row6) * 48 + c6 * 8);
            *(bf16x8*)(ct + row6 * 72 + c6 * 8) = v;
        }
        const int rz = tid / 3, cz = tid - rz * 3;
        if (tid < 96) {
            bf16x8 z;
            #pragma unroll
            for (int i = 0; i < 8; ++i) z[i] = (__bf16)0.0f;
            *(bf16x8*)(ct + rz * 72 + 48 + cz * 8) = z;
        }
    }
    __syncthreads();

    const int l15 = lane & 15, q4 = lane >> 4;
    const int rt = wave >> 1, g = wave & 1;
    f32x4 acc[6];
    #pragma unroll
    for (int j = 0; j < 6; ++j) acc[j] = (f32x4){0.f, 0.f, 0.f, 0.f};
    const bf16* arow = ct + (rt * 16 + l15) * 72 + q4 * 8;
    #pragma unroll
    for (int kb = 0; kb < 2; ++kb) {
        const bf16x8 a = *(const bf16x8*)(arow + kb * 32);
        const bf16* wp = wrepo + ((size_t)kb * 192 + l15) * 32 + q4 * 8
                       + (size_t)(g * 6) * 16 * 32;
        #pragma unroll
        for (int j = 0; j < 6; ++j) {
            const bf16x8 bb = *(const bf16x8*)(wp + (size_t)j * 16 * 32);
            acc[j] = __builtin_amdgcn_mfma_f32_16x16x32_bf16(a, bb, acc[j], 0, 0, 0);
        }
    }

    const int rw0 = rowbase + rt * 16 + q4 * 4;
    float sum[4] = {0.f, 0.f, 0.f, 0.f}, ssum[4] = {0.f, 0.f, 0.f, 0.f};
    #pragma unroll
    for (int j = 0; j < 6; ++j) {
        const int col = (g * 6 + j) * 16 + l15;
        const float bod = bo[col];
        #pragma unroll
        for (int reg = 0; reg < 4; ++reg) {
            const float v = acc[j][reg] + bod + x[(size_t)(rw0 + reg) * D_ + col];
            acc[j][reg] = v;
            x2b[(size_t)(rw0 + reg) * D_ + col] = f2b(v);
            sum[reg] += v; ssum[reg] += v * v;
        }
    }
    #pragma unroll
    for (int m = 1; m <= 8; m <<= 1) {
        #pragma unroll
        for (int reg = 0; reg < 4; ++reg) {
            sum[reg]  += __shfl_xor(sum[reg], m, 64);
            ssum[reg] += __shfl_xor(ssum[reg], m, 64);
        }
    }
    if (l15 == 0) {
        #pragma unroll
        for (int reg = 0; reg < 4; ++reg) {
            psum[wave][q4][reg][0] = sum[reg];
            psum[wave][q4][reg][1] = ssum[reg];
        }
    }
    __syncthreads();
    float mean[4], rs[4];
    #pragma unroll
    for (int reg = 0; reg < 4; ++reg) {
        const float st  = sum[reg]  + psum[wave ^ 1][q4][reg][0];
        const float qt2 = ssum[reg] + psum[wave ^ 1][q4][reg][1];
        mean[reg] = st * (1.0f / 192.0f);
        const float var = qt2 * (1.0f / 192.0f) - mean[reg] * mean[reg];
        rs[reg] = rsqrtf(var + EPS_);
    }
    #pragma unroll
    for (int j = 0; j < 6; ++j) {
        const int col = (g * 6 + j) * 16 + l15;
        const float gg = g2[col], bb2 = lb2[col];
        #pragma unroll
        for (int reg = 0; reg < 4; ++reg)
            xn2b[(size_t)(rw0 + reg) * D_ + col] =
                f2b((acc[j][reg] - mean[reg]) * rs[reg] * gg + bb2);
    }
}

// ---------------------------------------------------------------------------
// K4: FUSED conv1+conv2 (unchanged from round 5; INROWB=416).
// ---------------------------------------------------------------------------
#define INROWB 416            // LDS row stride in bytes (384 data + 32 pad)
#define NIN    36             // staged input rows (rowbase-2 .. rowbase+33)
#define NH     34             // h rows (positions lrow-1 .. lrow+32)
#define HTOFF  (NIN * INROWB)
__global__ __launch_bounds__(256, 4) void k_conv_fused(
    const bf16* __restrict__ act, const bf16* __restrict__ w1,
    const float* __restrict__ b1c, const bf16* __restrict__ w2,
    const float* __restrict__ b2c, const bf16* __restrict__ x2b,
    float* __restrict__ outf)
{
    __shared__ __align__(16) char lds[NIN * INROWB + NH * INROWB];   // 29120 B

    const int tid = threadIdx.x;
    const int wave = tid >> 6, lane = tid & 63;
    const int m16 = lane & 15, q = lane >> 4;
    const int rowbase = blockIdx.x * 32;
    const int lrow = rowbase & (L_ - 1);

    // ---- stage xn2b rows rowbase-2 .. rowbase+33 (36 rows x 384 B) ----
    {
        const bf16* src0 = act + ((long long)rowbase - 2) * D_;
        bf16x8 v[4];
        int dst[4];
        #pragma unroll
        for (int i = 0; i < 4; ++i) {
            const int g = tid + i * 256;
            if (g < 864) {
                v[i] = *(const bf16x8*)(src0 + g * 8);
                const int row = (g * 2731) >> 16;          // g / 24
                dst[i] = row * INROWB + (g - row * 24) * 16;
            }
        }
        #pragma unroll
        for (int i = 0; i < 4; ++i) {
            const int g = tid + i * 256;
            if (g < 864) *(bf16x8*)(lds + dst[i]) = v[i];
        }
    }

    const int laneA = m16 * INROWB + q * 16;  // per-lane A-fragment byte offset
    const int colw = wave * 48;
    float bd1[3], bd2[3];
    #pragma unroll
    for (int j = 0; j < 3; ++j) {
        bd1[j] = b1c[colw + j * 16 + m16];
        bd2[j] = b2c[colw + j * 16 + m16];
    }
    __syncthreads();

    // ---- conv1: 3 M-tiles (48 rows, 34 valid) x 3 N-tiles, K=576 ----
    f32x4 acc1[3][3];
    #pragma unroll
    for (int mt = 0; mt < 3; ++mt)
        #pragma unroll
        for (int j = 0; j < 3; ++j) acc1[mt][j] = (f32x4){0.f, 0.f, 0.f, 0.f};

    #define LOADB(w, kb, j) \
        (*(const bf16x8*)((w) + ((size_t)(kb) * 192 + m16) * 32 + q * 8 \
                          + (size_t)(wave * 3 + (j)) * 16 * 32))
    {
        bf16x8 bB[2][3];
        #pragma unroll
        for (int j = 0; j < 3; ++j) bB[0][j] = LOADB(w1, 0, j);
        #pragma unroll
        for (int kb = 0; kb < 18; ++kb) {
            if (kb + 1 < 18) {
                #pragma unroll
                for (int j = 0; j < 3; ++j) bB[(kb + 1) & 1][j] = LOADB(w1, kb + 1, j);
            }
            const int t = kb / 6, c6 = kb % 6;
            bf16x8 a[3];
            #pragma unroll
            for (int mt = 0; mt < 3; ++mt)
                a[mt] = *(const bf16x8*)(lds + laneA + (mt * 16 + t) * INROWB + c6 * 64);
            #pragma unroll
            for (int j = 0; j < 3; ++j)
                #pragma unroll
                for (int mt = 0; mt < 3; ++mt)
                    acc1[mt][j] = __builtin_amdgcn_mfma_f32_16x16x32_bf16(
                        a[mt], bB[kb & 1][j], acc1[mt][j], 0, 0, 0);
        }
    }

    // ---- h-tile (relu, edge-zero) -> LDS rows 0..33 ----
    #pragma unroll
    for (int mt = 0; mt < 3; ++mt)
        #pragma unroll
        for (int j = 0; j < 3; ++j)
            #pragma unroll
            for (int reg = 0; reg < 4; ++reg) {
                const int hr = mt * 16 + q * 4 + reg;
                if (hr < NH) {
                    const int hm = lrow + hr - 1;
                    float v = fmaxf(acc1[mt][j][reg] + bd1[j], 0.f);
                    if (hm == 0 || hm == L_ - 1) v = 0.f;
                    *(bf16*)(lds + HTOFF + hr * INROWB + (colw + j * 16 + m16) * 2) = f2b(v);
                }
            }

    // ---- preload residual x2b (latency hidden under barrier + conv2) ----
    float xr[3][2][4];
    #pragma unroll
    for (int j = 0; j < 3; ++j)
        #pragma unroll
        for (int mt = 0; mt < 2; ++mt)
            #pragma unroll
            for (int reg = 0; reg < 4; ++reg)
                xr[j][mt][reg] = b2f(x2b[(size_t)(rowbase + mt * 16 + q * 4 + reg) * D_
                                         + colw + j * 16 + m16]);
    __syncthreads();

    // ---- conv2: 2 M-tiles x 3 N-tiles, A from h-tile ----
    f32x4 acc2[2][3];
    #pragma unroll
    for (int mt = 0; mt < 2; ++mt)
        #pragma unroll
        for (int j = 0; j < 3; ++j) acc2[mt][j] = (f32x4){0.f, 0.f, 0.f, 0.f};
    {
        bf16x8 bB[2][3];
        #pragma unroll
        for (int j = 0; j < 3; ++j) bB[0][j] = LOADB(w2, 0, j);
        #pragma unroll
        for (int kb = 0; kb < 18; ++kb) {
            if (kb + 1 < 18) {
                #pragma unroll
                for (int j = 0; j < 3; ++j) bB[(kb + 1) & 1][j] = LOADB(w2, kb + 1, j);
            }
            const int t = kb / 6, c6 = kb % 6;
            bf16x8 a[2];
            #pragma unroll
            for (int mt = 0; mt < 2; ++mt)
                a[mt] = *(const bf16x8*)(lds + HTOFF + laneA + (mt * 16 + t) * INROWB + c6 * 64);
            #pragma unroll
            for (int j = 0; j < 3; ++j)
                #pragma unroll
                for (int mt = 0; mt < 2; ++mt)
                    acc2[mt][j] = __builtin_amdgcn_mfma_f32_16x16x32_bf16(
                        a[mt], bB[kb & 1][j], acc2[mt][j], 0, 0, 0);
        }
    }
    #undef LOADB

    // ---- epilogue: residual + store f32 ----
    #pragma unroll
    for (int j = 0; j < 3; ++j)
        #pragma unroll
        for (int mt = 0; mt < 2; ++mt)
            #pragma unroll
            for (int reg = 0; reg < 4; ++reg) {
                const int r = rowbase + mt * 16 + q * 4 + reg;
                const int m = r & (L_ - 1);
                float v = xr[j][mt][reg];
                if (m != 0 && m != L_ - 1) v += acc2[mt][j][reg] + bd2[j];
                outf[(size_t)r * D_ + colw + j * 16 + m16] = v;
            }
}

// ---------------------------------------------------------------------------
extern "C" void kernel_launch(void* const* d_in, const int* in_sizes, int n_in,
                              void* d_out, int out_size, void* d_ws, size_t ws_size,
                              hipStream_t stream)
{
    const float* x    = (const float*)d_in[0];
    const float* ln1g = (const float*)d_in[1];
    const float* ln1b = (const float*)d_in[2];
    const float* wq   = (const float*)d_in[3];
    const float* bq   = (const float*)d_in[4];
    const float* wk   = (const float*)d_in[5];
    const float* bk   = (const float*)d_in[6];
    const float* wv   = (const float*)d_in[7];
    const float* bv   = (const float*)d_in[8];
    const float* wo   = (const float*)d_in[9];
    const float* bo   = (const float*)d_in[10];
    const float* ln2g = (const float*)d_in[11];
    const float* ln2b = (const float*)d_in[12];
    const float* c1w  = (const float*)d_in[13];
    const float* c1b  = (const float*)d_in[14];
    const float* c2w  = (const float*)d_in[15];
    const float* c2b  = (const float*)d_in[16];

    const size_t ROWS = (size_t)16 * L_;            // 32768
    char* ws = (char*)d_ws;
    size_t off = 4096;                               // guard (conv halo row -2)
    bf16* xn2b = (bf16*)(ws + off); off += ROWS * D_ * 2;    // 12.6 MB
    off += 4096;                                     // guard (conv halo row +33)
    bf16* hpb  = (bf16*)(ws + off); off += ROWS * D_ * 2;    // (unused, keeps guard)
    off += 4096;                                     // guard
    bf16* x2b  = (bf16*)(ws + off); off += ROWS * D_ * 2;    // 12.6 MB
    f16* qb    = (f16*)(ws + off);   off += ROWS * HK_ * 2;  // 3.15 MB
    f16* kb    = (f16*)(ws + off);   off += ROWS * HK_ * 2;
    f16* vt    = (f16*)(ws + off);   off += (size_t)64 * 16 * 2048 * 2;   // 4.19 MB
    bf16* ctx  = (bf16*)(ws + off);  off += ROWS * 48 * 2;   // 3.15 MB (final ctx)
    bf16* wrep1 = (bf16*)(ws + off); off += 576 * 192 * 2;   // 221 KB
    bf16* wrep2 = (bf16*)(ws + off); off += 576 * 192 * 2;
    bf16* wrepq = (bf16*)(ws + off); off += 6 * 144 * 32 * 2;
    float* bias144 = (float*)(ws + off); off += 144 * 4;
    bf16* wrepo = (bf16*)(ws + off); off += 2 * 192 * 32 * 2;

    (void)hpb;
    k_prep_all   <<<1021, 256, 0, stream>>>(c1w, c2w, wq, wk, wv, bq, bk, bv, wo,
                                            wrep1, wrep2, wrepq, bias144, wrepo);
    k_ln_qkv     <<<1024, 256, 0, stream>>>(x, ln1g, ln1b, wrepq, bias144, qb, kb, vt);
    k_attn       <<<2048, 256, 0, stream>>>(qb, kb, vt, ctx);
    k_proj_ln2   <<<1024, 256, 0, stream>>>(x, ctx, wrepo, bo, ln2g, ln2b,
                                            x2b, xn2b);
    k_conv_fused <<<1024, 256, 0, stream>>>(xn2b, wrep1, c1b, wrep2, c2b, x2b,
                                            (float*)d_out);
}

// Round 7
// 193.070 us; speedup vs baseline: 1.2520x; 1.2520x over previous
//
#include <hip/hip_runtime.h>
#include <hip/hip_bf16.h>

#define L_ 2048
#define D_ 192
#define HK_ 48
#define EPS_ 1e-3f
#define SCALE_ 0.28867513459481287f  // 1/sqrt(12)
#define LOG2E_ 1.4426950408889634f

typedef __hip_bfloat16 bf16;
typedef _Float16 f16;
typedef __fp16 hf16x2 __attribute__((ext_vector_type(2)));   // builtin return type
typedef _Float16 f16x4 __attribute__((ext_vector_type(4)));
typedef __bf16 bf16x4 __attribute__((ext_vector_type(4)));
typedef __bf16 bf16x8 __attribute__((ext_vector_type(8)));
typedef float  f32x4  __attribute__((ext_vector_type(4)));

__device__ __forceinline__ float b2f(bf16 x) { return __bfloat162float(x); }
__device__ __forceinline__ bf16 f2b(float x) { return __float2bfloat16(x); }

// ---------------------------------------------------------------------------
// K0: single prep kernel — all weight repacks in one launch (unchanged).
// ---------------------------------------------------------------------------
__global__ __launch_bounds__(256) void k_prep_all(
    const float* __restrict__ c1w, const float* __restrict__ c2w,
    const float* __restrict__ wq, const float* __restrict__ wk, const float* __restrict__ wv,
    const float* __restrict__ bq, const float* __restrict__ bk, const float* __restrict__ bv,
    const float* __restrict__ wo,
    bf16* __restrict__ wrep1, bf16* __restrict__ wrep2,
    bf16* __restrict__ wrepq, float* __restrict__ bias144, bf16* __restrict__ wrepo)
{
    const int i = blockIdx.x * 256 + threadIdx.x;
    if (i < 110592) {
        const int k = i / 192, n = i - k * 192;
        wrep1[((size_t)(k >> 5) * 192 + n) * 32 + (k & 31)] = f2b(c1w[i]);
    } else if (i < 221184) {
        const int j = i - 110592;
        const int k = j / 192, n = j - k * 192;
        wrep2[((size_t)(k >> 5) * 192 + n) * 32 + (k & 31)] = f2b(c2w[j]);
    } else if (i < 248832) {
        const int j = i - 221184;
        const int kb = j / 4608, rem = j % 4608;
        const int n = rem / 32, kk = rem % 32;
        const int k = kb * 32 + kk;
        float v;
        if (n < 48)       v = wq[k * HK_ + n] * (SCALE_ * LOG2E_);
        else if (n < 96)  v = wk[k * HK_ + (n - 48)];
        else              v = wv[k * HK_ + (n - 96)];
        wrepq[j] = f2b(v);
    } else if (i < 248976) {
        const int j = i - 248832;
        bias144[j] = (j < 48) ? bq[j] * (SCALE_ * LOG2E_)
                   : (j < 96) ? bk[j - 48] : bv[j - 96];
    } else if (i < 261264) {
        const int j = i - 248976;
        const int kb = j / 6144, rem = j % 6144;
        const int n = rem / 32, kk = rem % 32;
        const int k = kb * 32 + kk;
        wrepo[j] = f2b(k < 48 ? wo[k * D_ + n] : 0.f);
    }
}

// ---------------------------------------------------------------------------
// K1: fused LN1 + QKV projection via MFMA (r4 version; q/k head-contiguous
// [b*4+h][2048][12]).
// ---------------------------------------------------------------------------
__global__ __launch_bounds__(256, 4) void k_ln_qkv(
    const float* __restrict__ x, const float* __restrict__ g1, const float* __restrict__ b1,
    const bf16* __restrict__ wrep, const float* __restrict__ bias144,
    f16* __restrict__ qo, f16* __restrict__ ko, f16* __restrict__ vt)
{
    __shared__ bf16 xn[32 * 200];
    const int tid = threadIdx.x;
    const int wave = tid >> 6, lane = tid & 63;
    const int rowbase = blockIdx.x * 32;
    const int b = rowbase >> 11;
    const int lrow0 = rowbase & 2047;

    const float gg0 = g1[lane], gg1 = g1[lane + 64], gg2 = g1[lane + 128];
    const float bb0 = b1[lane], bb1 = b1[lane + 64], bb2 = b1[lane + 128];
    for (int i = 0; i < 8; ++i) {
        const int r = wave * 8 + i;
        const float* xp = x + (size_t)(rowbase + r) * D_;
        const float x0 = xp[lane];
        const float x1 = xp[lane + 64];
        const float x2 = xp[lane + 128];
        float s = x0 + x1 + x2;
        float q = x0 * x0 + x1 * x1 + x2 * x2;
        #pragma unroll
        for (int m = 1; m < 64; m <<= 1) {
            s += __shfl_xor(s, m, 64);
            q += __shfl_xor(q, m, 64);
        }
        const float mean = s * (1.0f / 192.0f);
        const float var  = q * (1.0f / 192.0f) - mean * mean;
        const float rs   = rsqrtf(var + EPS_);
        xn[r * 200 + lane]       = f2b((x0 - mean) * rs * gg0 + bb0);
        xn[r * 200 + lane + 64]  = f2b((x1 - mean) * rs * gg1 + bb1);
        xn[r * 200 + lane + 128] = f2b((x2 - mean) * rs * gg2 + bb2);
    }

    if (tid < 128) {
        const int h  = tid >> 5;
        const int vc = 12 + ((tid >> 3) & 3);
        const int p0 = lrow0 + (tid & 7) * 4;
        f16x4 vv;
        vv[0] = vv[1] = vv[2] = vv[3] = (vc == 12) ? (f16)1.0f : (f16)0.0f;
        *(f16x4*)(vt + ((size_t)(b * 4 + h) * 16 + vc) * 2048 + p0) = vv;
    }
    __syncthreads();

    const int l15 = lane & 15, q4 = lane >> 4;
    const int rt = wave >> 1, g = wave & 1;
    const int ntlim = 5 - g;                 // g=0: nt 0..4, g=1: nt 0..3 (+5)
    f32x4 acc[5];
    #pragma unroll
    for (int nt = 0; nt < 5; ++nt) acc[nt] = (f32x4){0.f, 0.f, 0.f, 0.f};

    const bf16* xrow = xn + (rt * 16 + l15) * 200 + q4 * 8;
    #pragma unroll
    for (int kb = 0; kb < 6; ++kb) {
        const bf16x8 a = *(const bf16x8*)(xrow + kb * 32);
        const bf16* wp = wrep + ((size_t)kb * 144 + l15) * 32 + q4 * 8
                       + (size_t)(g * 5) * 16 * 32;
        #pragma unroll
        for (int nt = 0; nt < 5; ++nt) {
            if (nt < ntlim) {
                const bf16x8 bfr = *(const bf16x8*)(wp + (size_t)nt * 16 * 32);
                acc[nt] = __builtin_amdgcn_mfma_f32_16x16x32_bf16(a, bfr, acc[nt], 0, 0, 0);
            }
        }
    }

    const int lr0 = lrow0 + rt * 16 + q4 * 4;
    #pragma unroll
    for (int nt = 0; nt < 5; ++nt) {
        if (nt < ntlim) {
            const int ntg = g * 5 + nt;
            const int col = ntg * 16 + l15;
            const float bd = bias144[col];
            if (ntg < 3) {
                const int h2 = col / 12, c12 = col - h2 * 12;
                #pragma unroll
                for (int reg = 0; reg < 4; ++reg)
                    qo[((size_t)(b * 4 + h2) * 2048 + lr0 + reg) * 12 + c12] =
                        (f16)(acc[nt][reg] + bd);
            } else if (ntg < 6) {
                const int ck = col - 48;
                const int h2 = ck / 12, c12 = ck - h2 * 12;
                #pragma unroll
                for (int reg = 0; reg < 4; ++reg)
                    ko[((size_t)(b * 4 + h2) * 2048 + lr0 + reg) * 12 + c12] =
                        (f16)(acc[nt][reg] + bd);
            } else {
                const int vcol = col - 96;
                const int h = vcol / 12, c12 = vcol % 12;
                f16x4 vv;
                #pragma unroll
                for (int reg = 0; reg < 4; ++reg) vv[reg] = (f16)(acc[nt][reg] + bd);
                *(f16x4*)(vt + ((size_t)(b * 4 + h) * 16 + c12) * 2048 +
                          lrow0 + rt * 16 + q4 * 4) = vv;
            }
        }
    }
}

// ---------------------------------------------------------------------------
// K2: REVERTED to split-k partials attention (r4 version). Flash variants
// measured 63/87 µs because per-load MFMA work dropped 2-4x vs this design
// (64 q-rows/wave = 4 MFMA-pairs per K/V load, 2304 balanced blocks,
// <=16-tile loops). head-contiguous q/k, exp2 softmax.
// ---------------------------------------------------------------------------
__global__ __launch_bounds__(256, 8) void k_attn_part(
    const f16* __restrict__ qh, const f16* __restrict__ kh, const f16* __restrict__ vt,
    bf16* __restrict__ part_o, float* __restrict__ part_l)
{
    const int tid = threadIdx.x;
    const int wv = tid >> 6, lane = tid & 63;
    const int quad = lane >> 4, l15 = lane & 15;
    const int bh = blockIdx.x / 36;
    int r = blockIdx.x % 36;
    int qt = 0;
    while (r >= qt + 1) { r -= qt + 1; ++qt; }
    const int ks = r;
    const size_t base  = (size_t)bh * 2048 * 12;          // head-contiguous
    const size_t vbase = ((size_t)bh * 16 + l15) * 2048;
    const int kbase = ks * 256;
    const int qbase = qt * 256 + wv * 64;
    const bool diag = (ks == qt);
    const int ktmax = diag ? 4 * (wv + 1) : 16;

    f16x4 Qf[4];
    #pragma unroll
    for (int s = 0; s < 4; ++s) {
        f16x4 v;
        if (quad < 3)
            v = *(const f16x4*)(qh + base + (size_t)(qbase + s * 16 + l15) * 12 + quad * 4);
        else { v[0] = (f16)LOG2E_; v[1] = 0; v[2] = 0; v[3] = 0; }   // hd12 = log2e
        Qf[s] = v;
    }

    f32x4 O[4];
    #pragma unroll
    for (int s = 0; s < 4; ++s) O[s] = (f32x4){0.f, 0.f, 0.f, 0.f};

    for (int g = 0; g < ktmax; g += 2) {
        f16x4 Kg[2], Vg[2];
        #pragma unroll
        for (int u = 0; u < 2; ++u) {
            const int kt = g + u;
            f16x4 kf;
            if (quad < 3)
                kf = *(const f16x4*)(kh + base + (size_t)(kbase + kt * 16 + l15) * 12 + quad * 4);
            else { kf[0] = (f16)-6.0f; kf[1] = 0; kf[2] = 0; kf[3] = 0; } // hd12 = -6
            Kg[u] = kf;
            Vg[u] = *(const f16x4*)(vt + vbase + kbase + kt * 16 + quad * 4);
        }
        #pragma unroll
        for (int u = 0; u < 2; ++u) {
            const int k0 = kbase + (g + u) * 16 + quad * 4;
            #pragma unroll
            for (int s = 0; s < 4; ++s) {
                f32x4 sc = (f32x4){0.f, 0.f, 0.f, 0.f};
                sc = __builtin_amdgcn_mfma_f32_16x16x16f16(Kg[u], Qf[s], sc, 0, 0, 0);
                float p0 = __builtin_amdgcn_exp2f(sc[0]);
                float p1 = __builtin_amdgcn_exp2f(sc[1]);
                float p2 = __builtin_amdgcn_exp2f(sc[2]);
                float p3 = __builtin_amdgcn_exp2f(sc[3]);
                if (diag) {
                    const int qg = qbase + s * 16 + l15;
                    p0 = (k0 + 0 <= qg) ? p0 : 0.f;
                    p1 = (k0 + 1 <= qg) ? p1 : 0.f;
                    p2 = (k0 + 2 <= qg) ? p2 : 0.f;
                    p3 = (k0 + 3 <= qg) ? p3 : 0.f;
                }
                const hf16x2 lo = __builtin_amdgcn_cvt_pkrtz(p0, p1);
                const hf16x2 hi = __builtin_amdgcn_cvt_pkrtz(p2, p3);
                f16x4 p;
                p[0] = (f16)lo[0]; p[1] = (f16)lo[1];
                p[2] = (f16)hi[0]; p[3] = (f16)hi[1];
                O[s] = __builtin_amdgcn_mfma_f32_16x16x16f16(p, Vg[u], O[s], 0, 0, 0);
            }
        }
    }

    const size_t pobase = (size_t)(bh * 8 + ks) * 2048;
    #pragma unroll
    for (int s = 0; s < 4; ++s) {
        const int q16 = qbase + s * 16;
        #pragma unroll
        for (int j = 0; j < 4; ++j) {
            const int qq = q16 + quad * 4 + j;
            if (l15 < 12)       part_o[(pobase + qq) * 12 + l15] = f2b(O[s][j]);
            else if (l15 == 12) part_l[pobase + qq] = O[s][j];
        }
    }
}

// ---------------------------------------------------------------------------
// K3: MEGA — combine + out-proj + residual + LN2 + conv1 + conv2 + residual,
// all in one kernel. Key idea: the conv halo (rows base-2..base+33) is
// RECOMPUTED in-block (proj/LN2 is row-independent and bit-identical across
// blocks), so the xn2b/x2b global round-trips (~54 MB) and one launch vanish.
// Clamped/garbage halo rows only feed h-rows that are edge-zeroed (hm==0 or
// L-1) or outputs that bypass conv (m==0 or L-1) — same argument verified in
// r2-r4. LDS 41.8 KB -> 3 blocks/CU. Conv input/h row stride 400 B (100 dw
// = 4 mod 32 -> b128 A-reads are 2-way aliased = free).
// ---------------------------------------------------------------------------
#define CIROWB 400
#define R2OFF  14400              // 36*400 : union { ct[48][72] | h-tile 34 rows }
#define X2OFF  28000              // R2OFF + 34*400
#define PSOFF  40288              // X2OFF + 32*192*2
__global__ __launch_bounds__(256, 3) void k_mega(
    const float* __restrict__ x, const bf16* __restrict__ part_o,
    const float* __restrict__ part_l, const bf16* __restrict__ wrepo,
    const float* __restrict__ bo, const float* __restrict__ g2,
    const float* __restrict__ lb2, const bf16* __restrict__ w1,
    const float* __restrict__ b1c, const bf16* __restrict__ w2,
    const float* __restrict__ b2c, float* __restrict__ outf)
{
    __shared__ __align__(16) char lds[41824];
    bf16* ct = (bf16*)(lds + R2OFF);          // [48][72] proj A-tile

    const int tid = threadIdx.x;
    const int wave = tid >> 6, lane = tid & 63;
    const int m16 = lane & 15, q = lane >> 4;
    const int rowbase = blockIdx.x * 32;
    const int b = rowbase >> 11, lrow = rowbase & 2047;
    const int colw = wave * 48;

    // ---- phase A0: combine partials for 36 halo rows (tile rows 0..35) ----
    if (tid < 144) {
        const int rr = tid >> 2, h = tid & 3;
        int qrow = lrow + rr - 2;
        qrow = qrow < 0 ? 0 : (qrow > 2047 ? 2047 : qrow);
        const int nsq = (qrow >> 8) + 1;       // segments valid for this row
        const size_t sb = (size_t)(b * 4 + h) * 8 * 2048 + qrow;
        float o[12];
        #pragma unroll
        for (int i = 0; i < 12; ++i) o[i] = 0.f;
        float l = 0.f;
        for (int s = 0; s < nsq; ++s) {
            l += part_l[sb + (size_t)s * 2048];
            const bf16x8 v8 = *(const bf16x8*)(part_o + (sb + (size_t)s * 2048) * 12);
            const bf16x4 v4 = *(const bf16x4*)(part_o + (sb + (size_t)s * 2048) * 12 + 8);
            #pragma unroll
            for (int i = 0; i < 8; ++i) o[i] += (float)v8[i];
            #pragma unroll
            for (int i = 0; i < 4; ++i) o[8 + i] += (float)v4[i];
        }
        const float inv = 1.0f / l;
        bf16* ctp = ct + rr * 72 + h * 12;
        #pragma unroll
        for (int i = 0; i < 12; ++i) ctp[i] = f2b(o[i] * inv);
        bf16x4 z;
        #pragma unroll
        for (int i = 0; i < 4; ++i) z[i] = (__bf16)0.0f;
        *(bf16x4*)(ct + rr * 72 + 48 + h * 4) = z;   // zero K-pad cols 48..63
    } else {
        const int idx = tid - 144;             // zero ct rows 36..47
        if (idx < 108) {
            bf16x8 z;
            #pragma unroll
            for (int i = 0; i < 8; ++i) z[i] = (__bf16)0.0f;
            *(bf16x8*)(ct + 36 * 72 + idx * 8) = z;
        }
    }
    float bd1[3], bd2[3], gg2[3], bbl2[3], bod[3];
    #pragma unroll
    for (int j = 0; j < 3; ++j) {
        const int col = colw + j * 16 + m16;
        bd1[j] = b1c[col]; bd2[j] = b2c[col];
        gg2[j] = g2[col];  bbl2[j] = lb2[col]; bod[j] = bo[col];
    }
    __syncthreads();

    // ---- phase A1: proj MFMA, 3 M-tiles (48 rows, 36 live) x 3 N-tiles ----
    f32x4 pv[3][3];
    #pragma unroll
    for (int mt = 0; mt < 3; ++mt)
        #pragma unroll
        for (int j = 0; j < 3; ++j) pv[mt][j] = (f32x4){0.f, 0.f, 0.f, 0.f};
    #pragma unroll
    for (int kb = 0; kb < 2; ++kb) {
        bf16x8 a[3];
        #pragma unroll
        for (int mt = 0; mt < 3; ++mt)
            a[mt] = *(const bf16x8*)(ct + (mt * 16 + m16) * 72 + kb * 32 + q * 8);
        #pragma unroll
        for (int j = 0; j < 3; ++j) {
            const bf16x8 bb = *(const bf16x8*)(wrepo +
                ((size_t)kb * 192 + (size_t)(wave * 3 + j) * 16 + m16) * 32 + q * 8);
            #pragma unroll
            for (int mt = 0; mt < 3; ++mt)
                pv[mt][j] = __builtin_amdgcn_mfma_f32_16x16x32_bf16(a[mt], bb, pv[mt][j], 0, 0, 0);
        }
    }

    // ---- bias + residual x -> v; per-row sum/ssq (48-col partial per wave) ----
    #pragma unroll
    for (int mt = 0; mt < 3; ++mt) {
        const bool live = (mt < 2) || (q == 0);
        #pragma unroll
        for (int j = 0; j < 3; ++j) {
            const int col = colw + j * 16 + m16;
            #pragma unroll
            for (int reg = 0; reg < 4; ++reg) {
                int grow = lrow + mt * 16 + q * 4 + reg - 2;
                grow = grow < 0 ? 0 : (grow > 2047 ? 2047 : grow);
                float v = 0.f;
                if (live)
                    v = pv[mt][j][reg] + bod[j] + x[((size_t)b * 2048 + grow) * D_ + col];
                pv[mt][j][reg] = v;
            }
        }
    }
    {
        float* ps = (float*)(lds + PSOFF);     // [4][48][2]
        #pragma unroll
        for (int mt = 0; mt < 3; ++mt) {
            float sum[4], ssq[4];
            #pragma unroll
            for (int reg = 0; reg < 4; ++reg) {
                sum[reg] = pv[mt][0][reg] + pv[mt][1][reg] + pv[mt][2][reg];
                ssq[reg] = pv[mt][0][reg] * pv[mt][0][reg]
                         + pv[mt][1][reg] * pv[mt][1][reg]
                         + pv[mt][2][reg] * pv[mt][2][reg];
            }
            #pragma unroll
            for (int m = 1; m <= 8; m <<= 1) {
                #pragma unroll
                for (int reg = 0; reg < 4; ++reg) {
                    sum[reg] += __shfl_xor(sum[reg], m, 64);
                    ssq[reg] += __shfl_xor(ssq[reg], m, 64);
                }
            }
            if (m16 == 0) {
                #pragma unroll
                for (int reg = 0; reg < 4; ++reg) {
                    const int tr = mt * 16 + q * 4 + reg;
                    ps[(wave * 48 + tr) * 2 + 0] = sum[reg];
                    ps[(wave * 48 + tr) * 2 + 1] = ssq[reg];
                }
            }
        }
    }
    __syncthreads();

    // ---- LN2 stats; write xn2 -> conv-input tile, v -> x2 tile ----
    {
        const float* ps = (const float*)(lds + PSOFF);
        #pragma unroll
        for (int mt = 0; mt < 3; ++mt) {
            const bool live = (mt < 2) || (q == 0);
            float mean[4], rs[4];
            #pragma unroll
            for (int reg = 0; reg < 4; ++reg) {
                const int tr = mt * 16 + q * 4 + reg;
                float st = 0.f, sq = 0.f;
                #pragma unroll
                for (int w = 0; w < 4; ++w) {
                    st += ps[(w * 48 + tr) * 2 + 0];
                    sq += ps[(w * 48 + tr) * 2 + 1];
                }
                mean[reg] = st * (1.0f / 192.0f);
                const float var = sq * (1.0f / 192.0f) - mean[reg] * mean[reg];
                rs[reg] = rsqrtf(var + EPS_);
            }
            if (live) {
                #pragma unroll
                for (int j = 0; j < 3; ++j) {
                    const int col = colw + j * 16 + m16;
                    #pragma unroll
                    for (int reg = 0; reg < 4; ++reg) {
                        const int tr = mt * 16 + q * 4 + reg;
                        const float v = pv[mt][j][reg];
                        const float xn = (v - mean[reg]) * rs[reg] * gg2[j] + bbl2[j];
                        *(bf16*)(lds + tr * CIROWB + col * 2) = f2b(xn);
                        if (tr >= 2 && tr < 34)
                            *(bf16*)(lds + X2OFF + ((tr - 2) * 192 + col) * 2) = f2b(v);
                    }
                }
            }
        }
    }
    __syncthreads();

    // ---- phase B: conv1 (3 M-tiles, 34 valid h rows) ----
    const int laneA = m16 * CIROWB + q * 16;
    f32x4 acc1[3][3];
    #pragma unroll
    for (int mt = 0; mt < 3; ++mt)
        #pragma unroll
        for (int j = 0; j < 3; ++j) acc1[mt][j] = (f32x4){0.f, 0.f, 0.f, 0.f};

    #define LOADB(w, kb, j) \
        (*(const bf16x8*)((w) + ((size_t)(kb) * 192 + m16) * 32 + q * 8 \
                          + (size_t)(wave * 3 + (j)) * 16 * 32))
    {
        bf16x8 bB[2][3];
        #pragma unroll
        for (int j = 0; j < 3; ++j) bB[0][j] = LOADB(w1, 0, j);
        #pragma unroll
        for (int kb = 0; kb < 18; ++kb) {
            if (kb + 1 < 18) {
                #pragma unroll
                for (int j = 0; j < 3; ++j) bB[(kb + 1) & 1][j] = LOADB(w1, kb + 1, j);
            }
            const int t = kb / 6, c6 = kb % 6;
            bf16x8 a[3];
            #pragma unroll
            for (int mt = 0; mt < 3; ++mt)
                a[mt] = *(const bf16x8*)(lds + laneA + (mt * 16 + t) * CIROWB + c6 * 64);
            #pragma unroll
            for (int j = 0; j < 3; ++j)
                #pragma unroll
                for (int mt = 0; mt < 3; ++mt)
                    acc1[mt][j] = __builtin_amdgcn_mfma_f32_16x16x32_bf16(
                        a[mt], bB[kb & 1][j], acc1[mt][j], 0, 0, 0);
        }
    }

    // ---- h-tile (relu, edge-zero) -> LDS region2 rows 0..33 ----
    #pragma unroll
    for (int mt = 0; mt < 3; ++mt)
        #pragma unroll
        for (int j = 0; j < 3; ++j)
            #pragma unroll
            for (int reg = 0; reg < 4; ++reg) {
                const int hr = mt * 16 + q * 4 + reg;
                if (hr < 34) {
                    const int hm = lrow + hr - 1;
                    float v = fmaxf(acc1[mt][j][reg] + bd1[j], 0.f);
                    if (hm == 0 || hm == L_ - 1) v = 0.f;
                    *(bf16*)(lds + R2OFF + hr * CIROWB + (colw + j * 16 + m16) * 2) = f2b(v);
                }
            }
    __syncthreads();

    // ---- conv2: 2 M-tiles x 3 N-tiles, A from h-tile ----
    f32x4 acc2[2][3];
    #pragma unroll
    for (int mt = 0; mt < 2; ++mt)
        #pragma unroll
        for (int j = 0; j < 3; ++j) acc2[mt][j] = (f32x4){0.f, 0.f, 0.f, 0.f};
    {
        bf16x8 bB[2][3];
        #pragma unroll
        for (int j = 0; j < 3; ++j) bB[0][j] = LOADB(w2, 0, j);
        #pragma unroll
        for (int kb = 0; kb < 18; ++kb) {
            if (kb + 1 < 18) {
                #pragma unroll
                for (int j = 0; j < 3; ++j) bB[(kb + 1) & 1][j] = LOADB(w2, kb + 1, j);
            }
            const int t = kb / 6, c6 = kb % 6;
            bf16x8 a[2];
            #pragma unroll
            for (int mt = 0; mt < 2; ++mt)
                a[mt] = *(const bf16x8*)(lds + R2OFF + laneA + (mt * 16 + t) * CIROWB + c6 * 64);
            #pragma unroll
            for (int j = 0; j < 3; ++j)
                #pragma unroll
                for (int mt = 0; mt < 2; ++mt)
                    acc2[mt][j] = __builtin_amdgcn_mfma_f32_16x16x32_bf16(
                        a[mt], bB[kb & 1][j], acc2[mt][j], 0, 0, 0);
        }
    }
    #undef LOADB

    // ---- epilogue: residual (x+mha from x2 tile) + conv2 + store f32 ----
    #pragma unroll
    for (int j = 0; j < 3; ++j)
        #pragma unroll
        for (int mt = 0; mt < 2; ++mt)
            #pragma unroll
            for (int reg = 0; reg < 4; ++reg) {
                const int orr = mt * 16 + q * 4 + reg;
                const int r = rowbase + orr;
                const int m = r & (L_ - 1);
                const int col = colw + j * 16 + m16;
                float v = b2f(*(const bf16*)(lds + X2OFF + (orr * 192 + col) * 2));
                if (m != 0 && m != L_ - 1) v += acc2[mt][j][reg] + bd2[j];
                outf[(size_t)r * D_ + col] = v;
            }
}

// ---------------------------------------------------------------------------
extern "C" void kernel_launch(void* const* d_in, const int* in_sizes, int n_in,
                              void* d_out, int out_size, void* d_ws, size_t ws_size,
                              hipStream_t stream)
{
    const float* x    = (const float*)d_in[0];
    const float* ln1g = (const float*)d_in[1];
    const float* ln1b = (const float*)d_in[2];
    const float* wq   = (const float*)d_in[3];
    const float* bq   = (const float*)d_in[4];
    const float* wk   = (const float*)d_in[5];
    const float* bk   = (const float*)d_in[6];
    const float* wv   = (const float*)d_in[7];
    const float* bv   = (const float*)d_in[8];
    const float* wo   = (const float*)d_in[9];
    const float* bo   = (const float*)d_in[10];
    const float* ln2g = (const float*)d_in[11];
    const float* ln2b = (const float*)d_in[12];
    const float* c1w  = (const float*)d_in[13];
    const float* c1b  = (const float*)d_in[14];
    const float* c2w  = (const float*)d_in[15];
    const float* c2b  = (const float*)d_in[16];

    const size_t ROWS = (size_t)16 * L_;            // 32768
    char* ws = (char*)d_ws;
    size_t off = 0;
    f16* qb    = (f16*)(ws + off);   off += ROWS * HK_ * 2;  // 3.15 MB
    f16* kb    = (f16*)(ws + off);   off += ROWS * HK_ * 2;
    f16* vt    = (f16*)(ws + off);   off += (size_t)64 * 16 * 2048 * 2;   // 4.19 MB
    bf16* part_o = (bf16*)(ws + off); off += (size_t)64 * 8 * 2048 * 12 * 2; // 25.2 MB
    float* part_l = (float*)(ws + off); off += (size_t)64 * 8 * 2048 * 4;    //  4.2 MB
    bf16* wrep1 = (bf16*)(ws + off); off += 576 * 192 * 2;   // 221 KB
    bf16* wrep2 = (bf16*)(ws + off); off += 576 * 192 * 2;
    bf16* wrepq = (bf16*)(ws + off); off += 6 * 144 * 32 * 2;
    float* bias144 = (float*)(ws + off); off += 144 * 4;
    bf16* wrepo = (bf16*)(ws + off); off += 2 * 192 * 32 * 2; // total ~37 MB

    k_prep_all  <<<1021, 256, 0, stream>>>(c1w, c2w, wq, wk, wv, bq, bk, bv, wo,
                                           wrep1, wrep2, wrepq, bias144, wrepo);
    k_ln_qkv    <<<1024, 256, 0, stream>>>(x, ln1g, ln1b, wrepq, bias144, qb, kb, vt);
    k_attn_part <<<64 * 36, 256, 0, stream>>>(qb, kb, vt, part_o, part_l);
    k_mega      <<<1024, 256, 0, stream>>>(x, part_o, part_l, wrepo, bo, ln2g, ln2b,
                                           wrep1, c1b, wrep2, c2b, (float*)d_out);
}